// Round 6
// baseline (232.576 us; speedup 1.0000x reference)
//
#include <hip/hip_runtime.h>
#include <hip/hip_bf16.h>

typedef __bf16 bf16x8 __attribute__((ext_vector_type(8)));
typedef float f32x4 __attribute__((ext_vector_type(4)));
typedef short short8 __attribute__((ext_vector_type(8)));
typedef short short4v __attribute__((ext_vector_type(4)));

#define NB 4
#define CC 256
#define SS 4096
#define EE 256

static constexpr float QSCALE = 1.4426950408889634f / 16.0f;  // log2(e)/sqrt(E)

// workspace offsets (bytes)
#define QOFF 0u
#define KOFF 8388608u
#define VOFF 16777216u
#define WOFF 25165824u
#define BOFF 25559040u
#define PAOFF 25690112u   // partial acc (f32 [slot][256 o][64 s]) then stats (float2 [slot][64 s])

#define GLOAD_LDS16(gsrc, ldst) \
    __builtin_amdgcn_global_load_lds((const __attribute__((address_space(1))) void*)(gsrc), \
                                     (__attribute__((address_space(3))) void*)(ldst), 16, 0, 0)

// ---------------- weight prep: fp32 -> bf16 (q rows pre-scaled) ----------------
__global__ __launch_bounds__(256) void prep_kernel(const float* __restrict__ Wq,
                                                   const float* __restrict__ bq,
                                                   const float* __restrict__ Wkv,
                                                   const float* __restrict__ bkv,
                                                   __bf16* __restrict__ wc,
                                                   float* __restrict__ bias) {
    int r = blockIdx.x;
    int t = threadIdx.x;
    float v;
    if (r < 256) v = Wq[r * 256 + t] * QSCALE;
    else         v = Wkv[(r - 256) * 256 + t];
    wc[r * 256 + t] = (__bf16)v;
    if (t == 0) bias[r] = (r < 256) ? bq[r] * QSCALE : bkv[r - 256];
}

// ---------------- projection: q,k [n][S][E] bf16 ; v transposed [n][O][S] bf16 ----------------
__global__ __launch_bounds__(256) void proj_kernel(const float* __restrict__ x,
                                                   const __bf16* __restrict__ wc,
                                                   const float* __restrict__ bias,
                                                   __bf16* __restrict__ qo,
                                                   __bf16* __restrict__ ko,
                                                   __bf16* __restrict__ vo) {
    __shared__ __align__(16) char Ab[32768];
    __shared__ __align__(16) char Wb[32768];
    const int t = threadIdx.x;
    const int lane = t & 63;
    const int w = t >> 6;
    const int n = blockIdx.x >> 6;
    const int s0 = (blockIdx.x & 63) << 6;

    {
        const int sl = t & 15;
        const int cc0 = t >> 4;
        #pragma unroll
        for (int it = 0; it < 2; ++it) {
            int c0 = (cc0 + (it << 4)) << 3;
            float f[8][4];
            #pragma unroll
            for (int r = 0; r < 8; ++r) {
                const float* xp = x + ((long)(n * CC + c0 + r)) * SS + s0 + sl;
                #pragma unroll
                for (int i = 0; i < 4; ++i) f[r][i] = xp[i << 4];
            }
            #pragma unroll
            for (int i = 0; i < 4; ++i) {
                bf16x8 v;
                #pragma unroll
                for (int r = 0; r < 8; ++r) v[r] = (__bf16)f[r][i];
                int srow = sl + (i << 4);
                *(bf16x8*)(Ab + srow * 512 + ((c0 * 2) ^ ((srow & 7) << 4))) = v;
            }
        }
    }
    __syncthreads();

    bf16x8 af[8];
    {
        int arow = (w << 4) + (lane & 15);
        #pragma unroll
        for (int kf = 0; kf < 8; ++kf) {
            int c = ((lane >> 4) << 3) + (kf << 5);
            af[kf] = *(const bf16x8*)(Ab + arow * 512 + ((c * 2) ^ ((arow & 7) << 4)));
        }
    }

    for (int ot = 0; ot < 12; ++ot) {
        #pragma unroll
        for (int p = 0; p < 16; ++p) {
            int row = w + (p << 2);
            int c = lane << 2;
            short4v vv = *(const short4v*)((const short*)wc + (ot * 64 + row) * 256 + c);
            *(short4v*)(Wb + row * 512 + ((c * 2) ^ ((row & 7) << 4))) = vv;
        }
        __syncthreads();

        f32x4 acc[4];
        #pragma unroll
        for (int cb = 0; cb < 4; ++cb) acc[cb] = (f32x4){0.f, 0.f, 0.f, 0.f};
        #pragma unroll
        for (int cb = 0; cb < 4; ++cb) {
            int row = (cb << 4) + (lane & 15);
            #pragma unroll
            for (int kf = 0; kf < 8; ++kf) {
                int c = ((lane >> 4) << 3) + (kf << 5);
                bf16x8 bfr = *(const bf16x8*)(Wb + row * 512 + ((c * 2) ^ ((row & 7) << 4)));
                acc[cb] = __builtin_amdgcn_mfma_f32_16x16x32_bf16(af[kf], bfr, acc[cb], 0, 0, 0);
            }
        }
        __syncthreads();

        __bf16* T = (__bf16*)Wb;
        float bsv[4];
        #pragma unroll
        for (int cb = 0; cb < 4; ++cb) bsv[cb] = bias[ot * 64 + (cb << 4) + (lane & 15)];

        if (ot < 8) {
            #pragma unroll
            for (int cb = 0; cb < 4; ++cb) {
                #pragma unroll
                for (int jj = 0; jj < 4; ++jj) {
                    int srow = (w << 4) + ((lane >> 4) << 2) + jj;
                    T[srow * 72 + (cb << 4) + (lane & 15)] = (__bf16)(acc[cb][jj] + bsv[cb]);
                }
            }
            __syncthreads();
            int s = t >> 2;
            int o0 = (t & 3) << 4;
            short8 r0 = *(const short8*)((const short*)T + s * 72 + o0);
            short8 r1 = *(const short8*)((const short*)T + s * 72 + o0 + 8);
            __bf16* dst = (ot < 4) ? qo : ko;
            long idx = ((long)(n * SS + s0 + s)) * EE + ((ot & 3) << 6) + o0;
            *(short8*)((short*)dst + idx) = r0;
            *(short8*)((short*)dst + idx + 8) = r1;
        } else {
            #pragma unroll
            for (int cb = 0; cb < 4; ++cb) {
                #pragma unroll
                for (int jj = 0; jj < 4; ++jj) {
                    int srow = (w << 4) + ((lane >> 4) << 2) + jj;
                    T[((cb << 4) + (lane & 15)) * 72 + srow] = (__bf16)(acc[cb][jj] + bsv[cb]);
                }
            }
            __syncthreads();
            int o = t >> 2;
            int sc0 = (t & 3) << 4;
            short8 r0 = *(const short8*)((const short*)T + o * 72 + sc0);
            short8 r1 = *(const short8*)((const short*)T + o * 72 + sc0 + 8);
            long idx = ((long)((n << 8) + ((ot - 8) << 6) + o)) * SS + s0 + sc0;
            *(short8*)((short*)vo + idx) = r0;
            *(short8*)((short*)vo + idx + 8) = r1;
        }
        __syncthreads();
    }
}

// ---------------- causal flash attention: KVBLK=32, double-buffered async KV, 1 barrier/tile ----------------
__global__ __launch_bounds__(256, 2) void attn_kernel(const __bf16* __restrict__ qg,
                                                      const __bf16* __restrict__ kg,
                                                      const __bf16* __restrict__ vg,
                                                      float* __restrict__ out,
                                                      float* __restrict__ pacc,
                                                      float2* __restrict__ pstats,
                                                      int ch32s, int mcshift, int direct) {
    __shared__ __align__(16) char Kb[2][16384];      // K tile [32][256] bf16, XOR-swizzled (16B slots ^ row&7)
    __shared__ __align__(16) char Vt[2][16384];      // V^T tile [256][32] bf16, slot ^ (o>>1)&3
    __shared__ __align__(16) __bf16 P[4][16][40];    // per-wave P buffer [16 q][32 k], padded
    const int t = threadIdx.x;
    const int lane = t & 63;
    const int w = t >> 6;

    const int b = blockIdx.x;                 // no XCD swizzle: causal work density varies with qt;
    const int c = b & ((1 << mcshift) - 1);   // plain round-robin balances XCDs
    const int qtn = b >> mcshift;
    const int qtr = qtn & 63;
    const int qt = 63 - qtr;                  // reversed: heavy q-tiles dispatch first
    const int n = qtn >> 6;
    const int jtop = (qt << 1) + 1;           // last kv32 tile index
    const int jlo = c << ch32s;
    if (jlo > jtop) return;
    const int CH = 1 << ch32s;
    const int jhi = (jtop < jlo + CH - 1) ? jtop : (jlo + CH - 1);
    const int s0 = qt << 6;
    const int wr_direct = direct || ((jtop >> ch32s) == 0);   // single-chunk q-tile: write out directly

    // async stage K[32][256] (pre-swizzled source -> linear LDS dest)
    auto stageK = [&](int jj, int pb) {
        const int t0 = jj << 5;
        #pragma unroll
        for (int i = 0; i < 4; ++i) {
            int r0 = (w << 3) + (i << 1);
            int rl = r0 + (lane >> 5);
            const short* src = (const short*)kg + ((long)(n * SS + t0 + rl)) * EE
                               + (((lane & 31) << 3) ^ ((rl & 7) << 3));
            GLOAD_LDS16(src, Kb[pb] + r0 * 512);
        }
    };
    // async stage V^T[256][32] from vo[n][o][s]; 16B slot swizzled by (o>>1)&3
    auto stageV = [&](int jj, int pb) {
        const int t0 = jj << 5;
        #pragma unroll
        for (int r = 0; r < 4; ++r) {
            int ob = (r << 6) + (w << 4);              // 16 rows per wave-iter
            int o = ob + (lane >> 2);
            int sp = lane & 3;
            const char* src = (const char*)vg + (((long)((n << 8) + o)) * SS + t0) * 2
                              + ((sp ^ ((o >> 1) & 3)) << 4);
            GLOAD_LDS16(src, Vt[pb] + (ob << 6));
        }
    };

    // Q fragments in registers
    bf16x8 qf[8];
    {
        int qrow = s0 + (w << 4) + (lane & 15);
        const short* qp = (const short*)qg + ((long)(n * SS + qrow)) * EE;
        #pragma unroll
        for (int kf = 0; kf < 8; ++kf) {
            int cc = ((lane >> 4) << 3) + (kf << 5);
            qf[kf] = *(const bf16x8*)(qp + cc);
        }
    }

    float m_[4], ls[4];
    #pragma unroll
    for (int rr = 0; rr < 4; ++rr) { m_[rr] = -3e38f; ls[rr] = 0.f; }
    f32x4 acc[16];
    #pragma unroll
    for (int ocb = 0; ocb < 16; ++ocb) acc[ocb] = (f32x4){0.f, 0.f, 0.f, 0.f};

    stageK(jlo, jlo & 1);
    stageV(jlo, jlo & 1);

    for (int jj = jlo; jj <= jhi; ++jj) {
        const int p = jj & 1;
        const int t0 = jj << 5;
        __syncthreads();            // vmcnt(0)+barrier: stage(jj) resident; buf[p^1] free (compute jj-1 done)

        if (jj < jhi) {             // issue next-tile stage NOW: latency hides under compute(jj)
            stageK(jj + 1, p ^ 1);
            stageV(jj + 1, p ^ 1);
        }

        // ---- S = Q K^T  (16 q x 32 k per wave)
        f32x4 sacc[2];
        sacc[0] = (f32x4){0.f, 0.f, 0.f, 0.f};
        sacc[1] = (f32x4){0.f, 0.f, 0.f, 0.f};
        #pragma unroll
        for (int cb = 0; cb < 2; ++cb) {
            int row = (cb << 4) + (lane & 15);
            #pragma unroll
            for (int kf = 0; kf < 8; ++kf) {
                int slot = (lane >> 4) + (kf << 2);
                bf16x8 kb = *(const bf16x8*)(Kb[p] + row * 512 + ((slot ^ (row & 7)) << 4));
                sacc[cb] = __builtin_amdgcn_mfma_f32_16x16x32_bf16(qf[kf], kb, sacc[cb], 0, 0, 0);
            }
        }

        if ((jj >> 1) == qt) {      // causal mask (diagonal spans 2 kv32 tiles)
            #pragma unroll
            for (int cb = 0; cb < 2; ++cb) {
                int key = t0 + (cb << 4) + (lane & 15);
                #pragma unroll
                for (int rr = 0; rr < 4; ++rr) {
                    int qr = s0 + (w << 4) + ((lane >> 4) << 2) + rr;
                    if (key > qr) sacc[cb][rr] = -1e30f;
                }
            }
        }

        // ---- online softmax (4 rows' chains interleaved)
        float mx[4], ps[4], scl[4];
        #pragma unroll
        for (int rr = 0; rr < 4; ++rr) mx[rr] = fmaxf(sacc[0][rr], sacc[1][rr]);
        #pragma unroll
        for (int off = 1; off < 16; off <<= 1) {
            #pragma unroll
            for (int rr = 0; rr < 4; ++rr) mx[rr] = fmaxf(mx[rr], __shfl_xor(mx[rr], off));
        }
        float pv[2][4];
        #pragma unroll
        for (int rr = 0; rr < 4; ++rr) {
            float mn = fmaxf(m_[rr], mx[rr]);
            scl[rr] = exp2f(m_[rr] - mn);
            m_[rr] = mn;
        }
        #pragma unroll
        for (int cb = 0; cb < 2; ++cb)
            #pragma unroll
            for (int rr = 0; rr < 4; ++rr) pv[cb][rr] = exp2f(sacc[cb][rr] - m_[rr]);
        #pragma unroll
        for (int rr = 0; rr < 4; ++rr) ps[rr] = pv[0][rr] + pv[1][rr];
        #pragma unroll
        for (int off = 1; off < 16; off <<= 1) {
            #pragma unroll
            for (int rr = 0; rr < 4; ++rr) ps[rr] += __shfl_xor(ps[rr], off);
        }
        #pragma unroll
        for (int rr = 0; rr < 4; ++rr) ls[rr] = ls[rr] * scl[rr] + ps[rr];

        // ---- P -> per-wave LDS
        #pragma unroll
        for (int cb = 0; cb < 2; ++cb)
            #pragma unroll
            for (int rr = 0; rr < 4; ++rr)
                P[w][((lane >> 4) << 2) + rr][(cb << 4) + (lane & 15)] = (__bf16)pv[cb][rr];

        #pragma unroll
        for (int ocb = 0; ocb < 16; ++ocb)
            #pragma unroll
            for (int rr = 0; rr < 4; ++rr) acc[ocb][rr] *= scl[rr];

        // ---- PV: P (own-wave LDS) x V^T (LDS)
        bf16x8 pa = *(const bf16x8*)&P[w][lane & 15][(lane >> 4) << 3];
        #pragma unroll
        for (int ocb = 0; ocb < 16; ++ocb) {
            int orow = (ocb << 4) + (lane & 15);
            bf16x8 vb = *(const bf16x8*)(Vt[p] + (orow << 6)
                                         + (((lane >> 4) ^ ((orow >> 1) & 3)) << 4));
            acc[ocb] = __builtin_amdgcn_mfma_f32_16x16x32_bf16(pa, vb, acc[ocb], 0, 0, 0);
        }
    }

    // ---- per-row stats (partial mode only)
    if (!wr_direct && (lane & 15) == 0) {
        #pragma unroll
        for (int rr = 0; rr < 4; ++rr) {
            int s = (w << 4) + ((lane >> 4) << 2) + rr;
            pstats[(long)b * 64 + s] = make_float2(m_[rr], ls[rr]);
        }
    }

    // ---- epilogue: transpose via LDS (reuse Kb, 32KB span), coalesced f32 writes.
    // HAND-UNROLLED over g: acc[] must only see compile-time indices (rule #20).
    float inv[4];
    #pragma unroll
    for (int rr = 0; rr < 4; ++rr) inv[rr] = wr_direct ? (1.0f / ls[rr]) : 1.0f;
    float* T = (float*)Kb;  // [64][68]

#define EPI_STAGE(g)                                                                   \
    do {                                                                               \
        __syncthreads();                                                               \
        _Pragma("unroll")                                                              \
        for (int q4 = 0; q4 < 4; ++q4) {                                               \
            int ol = (q4 << 4) + (lane & 15);                                          \
            _Pragma("unroll")                                                          \
            for (int rr = 0; rr < 4; ++rr)                                             \
                T[ol * 68 + (w << 4) + ((lane >> 4) << 2) + rr] =                      \
                    acc[((g) << 2) + q4][rr] * inv[rr];                                \
        }                                                                              \
        __syncthreads();                                                               \
        {                                                                              \
            int o = t >> 2;                                                            \
            int sc0 = (t & 3) << 4;                                                    \
            float* dp = wr_direct                                                      \
                ? (out + ((long)((n << 8) + ((g) << 6) + o)) * SS + s0 + sc0)          \
                : (pacc + (long)b * 16384 + (long)(((g) << 6) + o) * 64 + sc0);        \
            _Pragma("unroll")                                                          \
            for (int u = 0; u < 4; ++u) {                                              \
                f32x4 r = *(const f32x4*)(T + o * 68 + sc0 + (u << 2));                \
                *(f32x4*)(dp + (u << 2)) = r;                                          \
            }                                                                          \
        }                                                                              \
    } while (0)

    EPI_STAGE(0);
    EPI_STAGE(1);
    EPI_STAGE(2);
    EPI_STAGE(3);
#undef EPI_STAGE
}

// ---------------- combine partials (skips single-chunk q-tiles: written direct) ----------------
__global__ __launch_bounds__(256) void combine_kernel(const float* __restrict__ pacc,
                                                      const float2* __restrict__ pstats,
                                                      float* __restrict__ out,
                                                      int ch32s, int mcshift) {
    const int t = threadIdx.x;
    const int b = blockIdx.x;
    const int og = b & 3;
    const int qtr = (b >> 2) & 63;      // raw index (attn uses reversed qt)
    const int qt = 63 - qtr;
    const int n = b >> 8;
    const int jtop = (qt << 1) + 1;
    const int nch = (jtop >> ch32s) + 1;
    if (nch == 1) return;               // attn wrote these directly
    const long slotbase = (long)((n << 6) + qtr) << mcshift;

    __shared__ float wsc[8][64];
    __shared__ float invL[64];
    if (t < 64) {
        float M = -3e38f;
        for (int c2 = 0; c2 < nch; ++c2) M = fmaxf(M, pstats[(slotbase + c2) * 64 + t].x);
        float L = 0.f;
        for (int c2 = 0; c2 < nch; ++c2) {
            float2 st = pstats[(slotbase + c2) * 64 + t];
            float wv = exp2f(st.x - M);
            wsc[c2][t] = wv;
            L += st.y * wv;
        }
        invL[t] = 1.f / L;
    }
    __syncthreads();

    const int o = (og << 6) + (t >> 2);
    const int sb = (t & 3) << 4;
    f32x4 a[4];
    #pragma unroll
    for (int u = 0; u < 4; ++u) a[u] = (f32x4){0.f, 0.f, 0.f, 0.f};
    for (int c2 = 0; c2 < nch; ++c2) {
        const float* p = pacc + (slotbase + c2) * 16384 + (long)o * 64 + sb;
        #pragma unroll
        for (int u = 0; u < 4; ++u) {
            f32x4 v = *(const f32x4*)(p + (u << 2));
            #pragma unroll
            for (int k2 = 0; k2 < 4; ++k2) a[u][k2] += v[k2] * wsc[c2][sb + (u << 2) + k2];
        }
    }
    float* op = out + ((long)((n << 8) + o)) * SS + (qt << 6) + sb;
    #pragma unroll
    for (int u = 0; u < 4; ++u) {
        #pragma unroll
        for (int k2 = 0; k2 < 4; ++k2) a[u][k2] *= invL[sb + (u << 2) + k2];
        *(f32x4*)(op + (u << 2)) = a[u];
    }
}

extern "C" void kernel_launch(void* const* d_in, const int* in_sizes, int n_in,
                              void* d_out, int out_size, void* d_ws, size_t ws_size,
                              hipStream_t stream) {
    const float* x   = (const float*)d_in[0];
    const float* Wq  = (const float*)d_in[1];
    const float* bq  = (const float*)d_in[2];
    const float* Wkv = (const float*)d_in[3];
    const float* bkv = (const float*)d_in[4];
    float* out = (float*)d_out;
    char* ws = (char*)d_ws;
    __bf16* qw = (__bf16*)(ws + QOFF);
    __bf16* kw = (__bf16*)(ws + KOFF);
    __bf16* vw = (__bf16*)(ws + VOFF);
    __bf16* wc = (__bf16*)(ws + WOFF);
    float*  bias = (float*)(ws + BOFF);

    int mcshift = -1;
    for (int ms = 3; ms >= 0; --ms) {
        size_t slots = (size_t)256 << ms;
        size_t need = (size_t)PAOFF + slots * 65536 + slots * 512;
        if (need <= ws_size) { mcshift = ms; break; }
    }
    int direct = (mcshift < 0) ? 1 : 0;
    if (direct) mcshift = 0;
    int ch32s = 7 - mcshift;            // chunk = 2^ch32s kv32-tiles (128 kv32 tiles max per q-tile)
    float* pacc = (float*)(ws + PAOFF);
    float2* pstats = (float2*)(ws + PAOFF + (((size_t)256 << mcshift) * 65536));

    prep_kernel<<<dim3(768), dim3(256), 0, stream>>>(Wq, bq, Wkv, bkv, wc, bias);
    proj_kernel<<<dim3(256), dim3(256), 0, stream>>>(x, wc, bias, qw, kw, vw);
    attn_kernel<<<dim3(256 << mcshift), dim3(256), 0, stream>>>(qw, kw, vw, out, pacc, pstats,
                                                                ch32s, mcshift, direct);
    if (!direct)
        combine_kernel<<<dim3(1024), dim3(256), 0, stream>>>(pacc, pstats, out, ch32s, mcshift);
}